// Round 8
// baseline (320.154 us; speedup 1.0000x reference)
//
#include <hip/hip_runtime.h>
#include <math.h>

// Shift_11261404250938: per-image shift(trunc(±10%)) + zero-fill, standardize,
// min-max normalize. Standardization cancels in the min-max step, so
// out = (shifted - min) / (max - min).
//
// R9 -> R10: R9 only removed L1-HIT loads (no change, correctly so). No per-CU
// resource is saturated (VMEM 140cy/instr, 6.4 B/cy/CU transit vs fill's 10.7,
// VALU 5.5%) yet ALL structures pin at ~117us. The never-varied invariant:
// a chip-wide PURE-READ phase before any writes. fill(pure wr)=6.6 TB/s,
// copy(mixed)=6.29, ours(read-then-write)=2.6. Hypothesis: pure-read phases
// run at ~2 TB/s; mixed streams run at ~6. R10 makes BOTH passes copy-shaped:
//  - pass A: R0's proven flat gather body, but stores the RAW shifted value
//    (zeros included) and accumulates min/max of exactly what it stores;
//    8 blocks/image, block-reduce -> 2 encoded-uint atomics (order-preserving
//    float->uint map). Mix: 154MB rd + 154MB wr interleaved = m13's shape.
//  - pass B: in-place out = fma(out, inv, -mn*inv); reads L3-hot, writes HBM.
//    Same fma as every passing round -> numerics unchanged.
//  - ws: 2KB seeds via two hipMemsetAsync (0xFF=min slots, 0x00=max slots).
// Discriminator: if a total-HBM-traffic cap rules (462 vs 306MB), sum gets
// WORSE (~175us); if phase-shape rules, sum ~75-105us.

constexpr int kC = 3, kH = 224, kW = 224;
constexpr int kCHW  = kC * kH * kW;  // 150528
constexpr int kQPR  = kW / 4;        // 56 quads per row
constexpr int kNQ   = kC * kH * kQPR; // 37632 quads per image
constexpr int TB    = 256;           // 4 waves
constexpr int PARTS = 8;             // blocks per image
constexpr int WVB   = TB / 64;       // 4 waves per block

typedef float f32x4 __attribute__((ext_vector_type(4)));

// Order-preserving float -> uint encoding (monotone: a<b <=> enc(a)<enc(b)).
__device__ __forceinline__ unsigned enc_f(float f) {
    const unsigned u = __float_as_uint(f);
    return u ^ (((int)u >> 31) ? 0xFFFFFFFFu : 0x80000000u);
}
__device__ __forceinline__ float dec_f(unsigned e) {
    return __uint_as_float(e ^ ((e & 0x80000000u) ? 0x80000000u : 0xFFFFFFFFu));
}

__device__ __forceinline__ void shifts_for(const float* __restrict__ sfy,
                                           const float* __restrict__ sfx,
                                           int img, int& sy, int& sx)
{
    // Replicate reference fp32 order: ((f*2-1)*0.1f)*size, trunc toward zero.
    float ty = sfy[img] * 2.0f - 1.0f; ty *= 0.1f; ty *= (float)kH;
    sy = (int)truncf(ty);
    float tx = sfx[img] * 2.0f - 1.0f; tx *= 0.1f; tx *= (float)kW;
    sx = (int)truncf(tx);
}

// ---------------- Pass A: shifted copy + min/max (R0-proven gather) ----------
// Misaligned-by-sx gather as two aligned float4 loads + compile-time rotate
// (R = sx & 3; bases multiple of 4 -> clamped lanes' wrong elems always
// masked). Stores the RAW shifted value; accumulates min/max of stored data.
template <int R>
__device__ __forceinline__ void gatherA(const float* __restrict__ xb,
                                        float* __restrict__ ob,
                                        int sy, int sx, int f0,
                                        float& vmin, float& vmax)
{
    for (int f = f0; f < kNQ; f += PARTS * TB) {
        const int rr = f / kQPR;           // row in [0, C*H)
        const int q  = f - rr * kQPR;
        const int j  = rr % kH;            // row within channel
        const int c0 = rr - j;             // c * kH
        const int jj = j + sy;
        const bool rowok = (unsigned)jj < (unsigned)kH;
        const int jc = rowok ? jj : 0;     // clamp (masked anyway)
        const float* __restrict__ src = xb + (c0 + jc) * kW;

        const int i0 = q * 4;
        const int base = i0 + sx - R;      // multiple of 4
        int qa = base;     qa = qa < 0 ? 0 : qa; qa = qa > kW - 4 ? kW - 4 : qa;
        int qb = base + 4; qb = qb < 0 ? 0 : qb; qb = qb > kW - 4 ? kW - 4 : qb;
        const f32x4 av = *(const f32x4*)(src + qa);
        const f32x4 bv = *(const f32x4*)(src + qb);   // L1-hit neighbor line

        f32x4 o;
        #pragma unroll
        for (int k = 0; k < 4; ++k) {
            const float sel = (k + R < 4) ? av[k + R] : bv[k + R - 4];
            const int s = i0 + k + sx;     // source column
            const float v = (rowok && (unsigned)s < (unsigned)kW) ? sel : 0.0f;
            o[k] = v;                      // raw shifted value (zeros incl.)
            vmin = fminf(vmin, v);
            vmax = fmaxf(vmax, v);
        }
        *(f32x4*)(ob + rr * kW + i0) = o;  // 16B-aligned contiguous store
    }
}

__global__ __launch_bounds__(TB) void passA(
    const float* __restrict__ x, const float* __restrict__ sfy,
    const float* __restrict__ sfx, float* __restrict__ out,
    unsigned* __restrict__ umin, unsigned* __restrict__ umax)
{
    const int img  = blockIdx.x >> 3;          // PARTS = 8
    const int part = blockIdx.x & (PARTS - 1);
    const float* __restrict__ xb = x + (size_t)img * kCHW;
    float* __restrict__ ob = out + (size_t)img * kCHW;

    int sy, sx; shifts_for(sfy, sfx, img, sy, sx);

    float vmin = INFINITY, vmax = -INFINITY;
    const int f0 = part * TB + threadIdx.x;
    switch (sx & 3) {
        case 0: gatherA<0>(xb, ob, sy, sx, f0, vmin, vmax); break;
        case 1: gatherA<1>(xb, ob, sy, sx, f0, vmin, vmax); break;
        case 2: gatherA<2>(xb, ob, sy, sx, f0, vmin, vmax); break;
        default: gatherA<3>(xb, ob, sy, sx, f0, vmin, vmax); break;
    }

    // Wave (64-lane) shuffle reduction, then cross-wave via LDS.
    #pragma unroll
    for (int off = 32; off > 0; off >>= 1) {
        vmin = fminf(vmin, __shfl_down(vmin, off));
        vmax = fmaxf(vmax, __shfl_down(vmax, off));
    }
    __shared__ float smin[WVB], smax[WVB];
    const int tid = threadIdx.x;
    if ((tid & 63) == 0) { smin[tid >> 6] = vmin; smax[tid >> 6] = vmax; }
    __syncthreads();
    if (tid == 0) {
        float mn = smin[0], mx = smax[0];
        #pragma unroll
        for (int w = 1; w < WVB; ++w) {
            mn = fminf(mn, smin[w]);
            mx = fmaxf(mx, smax[w]);
        }
        atomicMin(&umin[img], enc_f(mn));   // device-scope, 8 per image total
        atomicMax(&umax[img], enc_f(mx));
    }
}

// ---------------- Pass B: in-place normalize (L3-hot read + HBM write) ------
__global__ __launch_bounds__(TB) void passB(
    float* __restrict__ out,
    const unsigned* __restrict__ umin, const unsigned* __restrict__ umax)
{
    const int img = blockIdx.x >> 3;
    const float mn = dec_f(umin[img]);         // uniform scalar loads
    const float mx = dec_f(umax[img]);
    const float inv  = 1.0f / (mx - mn);
    const float zoff = (0.0f - mn) * inv;
    float* __restrict__ ob = out + (size_t)img * kCHW;

    #pragma unroll 2
    for (int f = (blockIdx.x & (PARTS - 1)) * TB + threadIdx.x; f < kNQ;
         f += PARTS * TB) {
        f32x4 v = *(const f32x4*)(ob + f * 4);
        f32x4 o;
        #pragma unroll
        for (int k = 0; k < 4; ++k)
            o[k] = fmaf(v[k], inv, zoff);      // same fma as all prior rounds
        *(f32x4*)(ob + f * 4) = o;
    }
}

extern "C" void kernel_launch(void* const* d_in, const int* in_sizes, int n_in,
                              void* d_out, int out_size, void* d_ws, size_t ws_size,
                              hipStream_t stream) {
    const float* x  = (const float*)d_in[0];
    const float* fy = (const float*)d_in[1];
    const float* fx = (const float*)d_in[2];
    float* out = (float*)d_out;
    const int B = in_sizes[1];          // shift_fy has one element per image

    unsigned* umin = (unsigned*)d_ws;   // [B], seed 0xFFFFFFFF (enc +huge)
    unsigned* umax = umin + B;          // [B], seed 0x00000000 (enc -huge)
    hipMemsetAsync(umin, 0xFF, (size_t)B * sizeof(unsigned), stream);
    hipMemsetAsync(umax, 0x00, (size_t)B * sizeof(unsigned), stream);

    passA<<<B * PARTS, TB, 0, stream>>>(x, fy, fx, out, umin, umax);
    passB<<<B * PARTS, TB, 0, stream>>>(out, umin, umax);
}